// Round 11
// baseline (106.692 us; speedup 1.0000x reference)
//
#include <hip/hip_runtime.h>

#define C_    64
#define H_    40
#define W_    40
#define KS    11
#define HP    30          // H_ - KS + 1
#define NB    4
#define NL    900         // HP*HP
#define ND    59          // 2*(HP-1)+1
#define EPSF  1e-4f
#define PCH   3           // output rows per box job
#define SCW   65          // scratch row stride (odd -> conflict-free)
#define NINF  -3.4e38f
#define NBOXJ 1280        // 320*NB box jobs (exact cover at PCH=3)
#define SHB   34816       // 128*136*2 bytes: gram tile / norm overlay
#define TILEB 1600        // elements per 40x40 G tile

typedef _Float16 f16x8 __attribute__((ext_vector_type(8)));
typedef float    f32x4 __attribute__((ext_vector_type(4)));

// ===========================================================================
// k_A: blocks 0..675 = gram tiles -> G in 40x40-tile layout
//      Gt[b][mr][nc][r40][c40], tile idx = mr*40+nc, each tile 3200 B.
//      blocks 676..679 = per-batch invnorm.
// ===========================================================================
__global__ __launch_bounds__(256, 2)
void k_A(const float* __restrict__ im1, const float* __restrict__ im2,
         _Float16* __restrict__ G, float* __restrict__ invnorm) {
    __shared__ __align__(16) char sh[SHB];
    const int B = blockIdx.x, tid = threadIdx.x;

    if (B >= 676) {                       // ---- norm block ----
        const int b = B - 676;
        float* ssq = (float*)sh;          // 1600 f
        float* colsum = ssq + 1600;       // 1200 f
        const float* imb = im1 + b * C_ * 1600;
        for (int i = tid; i < 1600; i += 256) {
            float s = 0.f;
            #pragma unroll 8
            for (int c = 0; c < C_; ++c) { float v = imb[c * 1600 + i]; s += v * v; }
            ssq[i] = s;
        }
        __syncthreads();
        for (int t = tid; t < HP * W_; t += 256) {
            int yy = t / W_, x = t - yy * W_;
            float s = 0.f;
            #pragma unroll
            for (int r = 0; r < KS; ++r) s += ssq[(yy + r) * W_ + x];
            colsum[t] = s;
        }
        __syncthreads();
        for (int t = tid; t < NL; t += 256) {
            int ly = t / HP, lx = t - ly * HP;
            float s = 0.f;
            #pragma unroll
            for (int sx = 0; sx < KS; ++sx) s += colsum[ly * W_ + lx + sx];
            invnorm[b * NL + t] = 1.f / fmaxf(sqrtf(s), EPSF);
        }
        return;
    }

    // ---- gram tile ----
    const int b = B / 169, t0 = B - b * 169, i = t0 / 13, j = t0 - i * 13;
    int dd = i - j; if (dd < 0) dd = -dd;
    if (dd > 10) return;                  // outside the |m-n|<=1199 band

    _Float16* smem = (_Float16*)sh;
    _Float16 (*As)[128][8] = (_Float16 (*)[128][8])smem;
    _Float16 (*Bs)[128][8] = (_Float16 (*)[128][8])(smem + 8192);
    const int w = tid >> 6, L = tid & 63, lq = L >> 4, lr = L & 15;

    const float* p2 = im2 + b * C_ * 1600;   // A = im2 (rows/M)
    const float* p1 = im1 + b * C_ * 1600;   // B = im1 (cols/N)
    for (int t = tid; t < 1024; t += 256) {
        int oct = t >> 7, m = t & 127;
        int posA = i * 128 + m, posB = j * 128 + m;
        f16x8 ha = {}, hb = {};
        if (posA < 1600) {
            const float* pa = p2 + oct * 8 * 1600 + posA;
            #pragma unroll
            for (int k = 0; k < 8; ++k) ha[k] = (_Float16)pa[k * 1600];
        }
        if (posB < 1600) {
            const float* pb = p1 + oct * 8 * 1600 + posB;
            #pragma unroll
            for (int k = 0; k < 8; ++k) hb[k] = (_Float16)pb[k * 1600];
        }
        *(f16x8*)&As[oct][m][0] = ha;
        *(f16x8*)&Bs[oct][m][0] = hb;
    }
    __syncthreads();

    const int mb = (w & 1) * 64, nb = (w >> 1) * 64;
    f16x8 a0[4], a1[4], b0[4], b1[4];
    #pragma unroll
    for (int q = 0; q < 4; ++q) {
        a0[q] = *(const f16x8*)&As[lq][mb + q * 16 + lr][0];
        a1[q] = *(const f16x8*)&As[4 + lq][mb + q * 16 + lr][0];
        b0[q] = *(const f16x8*)&Bs[lq][nb + q * 16 + lr][0];
        b1[q] = *(const f16x8*)&Bs[4 + lq][nb + q * 16 + lr][0];
    }
    f32x4 acc[4][4];
    #pragma unroll
    for (int mi = 0; mi < 4; ++mi)
        #pragma unroll
        for (int ni = 0; ni < 4; ++ni) {
            f32x4 c = {0.f, 0.f, 0.f, 0.f};
            c = __builtin_amdgcn_mfma_f32_16x16x32_f16(a0[mi], b0[ni], c, 0, 0, 0);
            c = __builtin_amdgcn_mfma_f32_16x16x32_f16(a1[mi], b1[ni], c, 0, 0, 0);
            acc[mi][ni] = c;
        }
    __syncthreads();   // frags in regs; overlay C on smem
    // C layout: row (A/m) = quad*4+reg, col (B/n) = lane&15  [verified R3-R10]
    #pragma unroll
    for (int mi = 0; mi < 4; ++mi)
        #pragma unroll
        for (int ni = 0; ni < 4; ++ni)
            #pragma unroll
            for (int rg = 0; rg < 4; ++rg)
                smem[(mb + mi * 16 + lq * 4 + rg) * 136 + nb + ni * 16 + lr] =
                    (_Float16)acc[mi][ni][rg];
    __syncthreads();
    // scatter into tile layout; each 8-col segment lies in exactly one tile
    _Float16* Gb = G + (size_t)b * (1600 * TILEB);
    for (int t = tid; t < 2048; t += 256) {
        int row = t >> 4, seg = t & 15;
        int m = i * 128 + row, n = j * 128 + seg * 8;
        if (m < 1600 && n < 1600) {
            int mr = m / 40, r40 = m - mr * 40;
            int nc = n / 40, c40 = n - nc * 40;
            *(f16x8*)&Gb[(size_t)(mr * 40 + nc) * TILEB + r40 * 40 + c40] =
                *(const f16x8*)&smem[row * 136 + seg * 8];
        }
    }
}

// ===========================================================================
// k_B: one box job per block (P<=3 rows). Plane (y,dy) = contiguous tile
// y*41+dy (3.2 KB, coalesced). 2 barriers per row:
//   csum (regs->LDS) -> A -> diagonal running sums -> B -> wave0 max (shfl)
// Valid dxI range per px is exactly [29-px, 58-px] so no scratch init needed.
// ===========================================================================
__global__ __launch_bounds__(256, 6)
void k_B(const _Float16* __restrict__ G, const float* __restrict__ invnorm,
         float* __restrict__ part) {
    __shared__ float csum[1600];
    __shared__ float scratch[HP * SCW];
    __shared__ float sInv[PCH * HP];
    const int tid = threadIdx.x;

    // decode job id -> (b, dy, chunk); exact cover at PCH=3
    int c = blockIdx.x;
    int b = c / (NBOXJ / NB), r = c - b * (NBOXJ / NB), dy = 0, chunk = 0;
    for (int d = -(HP - 1); d <= HP - 1; ++d) {
        int ady = d < 0 ? -d : d;
        int n = (HP - ady + PCH - 1) / PCH;
        if (r < n) { dy = d; chunk = r; break; }
        r -= n;
    }
    const int ady = dy < 0 ? -dy : dy;
    const int rows = HP - ady;
    const int pyLo = dy < 0 ? -dy : 0;
    const int py0 = pyLo + chunk * PCH;
    const int P = min(PCH, rows - chunk * PCH);
    const int dyI = dy + (HP - 1);

    if (tid < P * HP) {
        int i = tid / HP, lx = tid - i * HP;
        sInv[i * HP + lx] = invnorm[b * NL + (py0 + i + dy) * HP + lx];
    }

    // plane p lives at tile (py0+p)*41 + dy; lane offset = tid*8
    const _Float16* base = G + ((size_t)b * 1600 + (size_t)(py0 * 41 + dy)) * TILEB
                             + tid * 8;
    const size_t PSTEP = (size_t)41 * TILEB;
    float s[8];
    f16x8 qa, qs;
    if (tid < 200) {
        #pragma unroll
        for (int j = 0; j < 8; ++j) s[j] = 0.f;
        for (int rr = 0; rr < KS; ++rr) {
            f16x8 q = *(const f16x8*)(base + rr * PSTEP);
            #pragma unroll
            for (int j = 0; j < 8; ++j) s[j] += (float)q[j];
        }
    }

    for (int i = 0; i < P; ++i) {
        const int py = py0 + i;
        if (tid < 200) {
            if (i > 0) {
                #pragma unroll
                for (int j = 0; j < 8; ++j) s[j] += (float)qa[j] - (float)qs[j];
            }
            float4* c4 = (float4*)(csum + tid * 8);
            c4[0] = make_float4(s[0], s[1], s[2], s[3]);
            c4[1] = make_float4(s[4], s[5], s[6], s[7]);
            if (i + 1 < P) {   // prefetch slide pair for iteration i+1
                qa = *(const f16x8*)(base + (i + 11) * PSTEP);
                qs = *(const f16x8*)(base + i * PSTEP);
            }
        }
        __syncthreads();                                   // A
        // diagonal 11-tap running sums; writes exactly the valid (px,dxI) set
        for (int t = tid; t < 5 * ND; t += 256) {
            int pg = t / ND, dxI = t - ND * pg;
            int dx = dxI - (HP - 1), pxb = 6 * pg;
            int u0 = max(0, -dx - pxb), u1 = min(5, (HP - 1) - dx - pxb);
            if (u0 <= u1) {
                const float* cp = csum + dx;
                float run = 0.f;
                #pragma unroll
                for (int sr = 0; sr < KS; ++sr) run += cp[(pxb + u0 + sr) * (W_ + 1)];
                int u = u0;
                for (;;) {
                    scratch[(pxb + u) * SCW + dxI] = run * sInv[i * HP + pxb + u + dx];
                    if (++u > u1) break;
                    run += cp[(pxb + u + 10) * (W_ + 1)] - cp[(pxb + u - 1) * (W_ + 1)];
                }
            }
        }
        __syncthreads();                                   // B
        // wave-0 max over the 30 valid dxI per px (2 lanes/px + shfl merge)
        if (tid < 60) {
            int px = tid >> 1, q = tid & 1;
            const float* sp = scratch + px * SCW + (HP - 1 - px) + q * 15;
            float m = NINF;
            #pragma unroll
            for (int d = 0; d < 15; ++d) m = fmaxf(m, sp[d]);
            m = fmaxf(m, __shfl_xor(m, 1, 64));
            if (q == 0) part[(((size_t)b * ND + dyI) * HP + py) * HP + px] = m;
        }
        // next iteration's barrier A orders the scratch/csum rewrites
    }
}

// ===========================================================================
// k_C: out[b,py,px] = max over the 30 valid dys: dyI in [29-py, 58-py]
// ===========================================================================
__global__ __launch_bounds__(256)
void k_C(const float* __restrict__ part, float* __restrict__ out) {
    int g = blockIdx.x * 256 + threadIdx.x;
    if (g >= NB * NL) return;
    int b = g / NL, l = g - b * NL, py = l / HP, px = l - py * HP;
    const float* p = part + (((size_t)b * ND + (HP - 1 - py)) * HP + py) * HP + px;
    float m = NINF;
    #pragma unroll
    for (int j = 0; j < HP; ++j) m = fmaxf(m, p[(size_t)j * HP * HP]);
    out[g] = m;
}

extern "C" void kernel_launch(void* const* d_in, const int* in_sizes, int n_in,
                              void* d_out, int out_size, void* d_ws, size_t ws_size,
                              hipStream_t stream) {
    const float* im1 = (const float*)d_in[0];
    const float* im2 = (const float*)d_in[1];
    float* out = (float*)d_out;
    float* invnorm = (float*)((char*)d_ws + 64);               // 14,400 B
    float* part = (float*)((char*)d_ws + 16384);               // 849,600 B
    _Float16* G = (_Float16*)((char*)d_ws + 1048576);          // 20,480,000 B

    k_A<<<680, 256, 0, stream>>>(im1, im2, G, invnorm);
    k_B<<<NBOXJ, 256, 0, stream>>>(G, invnorm, part);
    k_C<<<(NB * NL + 255) / 256, 256, 0, stream>>>(part, out);
}